// Round 3
// baseline (900.204 us; speedup 1.0000x reference)
//
#include <hip/hip_runtime.h>
#include <hip/hip_bf16.h>
#include <stdint.h>

#define VOCAB 32000
#define HID   256
#define BATCH 16
#define SEQT  256
#define ROWS  (BATCH*SEQT)   // 4096

typedef __attribute__((ext_vector_type(8))) short bf16x8_t;
typedef __attribute__((ext_vector_type(4))) float f32x4_t;

__device__ __forceinline__ short f2bs(float x) {
    __hip_bfloat16 h = __float2bfloat16(x);
    return *reinterpret_cast<short*>(&h);
}
__device__ __forceinline__ bf16x8_t cvt8(float4 a, float4 b) {
    union { short s[8]; bf16x8_t v; } u;
    u.s[0] = f2bs(a.x); u.s[1] = f2bs(a.y); u.s[2] = f2bs(a.z); u.s[3] = f2bs(a.w);
    u.s[4] = f2bs(b.x); u.s[5] = f2bs(b.y); u.s[6] = f2bs(b.z); u.s[7] = f2bs(b.w);
    return u.v;
}
// workgroup barrier draining ONLY lgkmcnt; vmem stays in flight
__device__ __forceinline__ void barrier_lds() {
    asm volatile("s_waitcnt lgkmcnt(0)\n\ts_barrier" ::: "memory");
}
// tanh via exp2: tanh(x) = 1 - 2/(2^(2*log2(e)*x)+1); saturates naturally.
__device__ __forceinline__ float tanh_exp(float x) {
    float e = __builtin_amdgcn_exp2f(x * 2.885390081777927f);
    return fmaf(-2.f, __builtin_amdgcn_rcpf(e + 1.f), 1.f);
}
// pack two f32 -> one dword of 2 bf16 (RNE), lo = first operand
__device__ __forceinline__ uint32_t pk_bf16(float lo, float hi) {
    uint32_t r;
    asm("v_cvt_pk_bf16_f32 %0, %1, %2" : "=v"(r) : "v"(lo), "v"(hi));
    return r;
}

// ===========================================================================
// Swizzled fragment layout (shared by A=hs and B=Wfcb):
//   element (row, k) -> swz[ (row>>4)*4096 + (k>>5)*512 + ((k>>3)&3)*128
//                            + (row&15)*8 + (k&7) ]
// A wave's MFMA fragment (one 16-row tile, one ki) is 1 KB CONTIGUOUS.
// ===========================================================================

// ---------------------------------------------------------------------------
// K1: xp[t][b][h] = Wih[inputs[b][t]][h]+bih[h]+bhh[h]; zeroes S; converts
// Wfc fp32 -> bf16 into SWIZZLED Wfcb (coalesced-write direction).
// ---------------------------------------------------------------------------
__global__ __launch_bounds__(256) void xproj_kernel(
    const int* __restrict__ inputs,
    const float* __restrict__ Wih,
    const float* __restrict__ bih,
    const float* __restrict__ bhh,
    const float* __restrict__ Wfc,
    float* __restrict__ xp,
    float* __restrict__ S,
    __hip_bfloat16* __restrict__ Wfcb,
    int do_cvt)
{
    int idx = blockIdx.x * 256 + threadIdx.x;  // (t*16+b)*256 + h
    int h  = idx & 255;
    int tb = idx >> 8;
    int b  = tb & 15;
    int t  = tb >> 4;
    int id = inputs[b * SEQT + t];
    xp[idx] = Wih[(size_t)id * HID + h] + bih[h] + bhh[h];
    if (idx < ROWS) S[idx] = 0.0f;
    if (do_cvt && idx < (VOCAB * HID / 8)) {
        // dst-linear: e = idx*8 shorts in swizzled Wfcb; decode -> (row,k)
        int e   = idx * 8;
        int m   = (e >> 3) & 15;
        int lhh = (e >> 7) & 3;
        int ki  = (e >> 9) & 7;
        int tile = e >> 12;
        const float4* p = (const float4*)(Wfc + (size_t)(tile * 16 + m) * HID
                                          + ki * 32 + lhh * 8);
        *(bf16x8_t*)((short*)Wfcb + (size_t)e) = cvt8(p[0], p[1]);
    }
}

// ---------------------------------------------------------------------------
// K2: RNN recurrence. One block, 256 threads (4 waves), M=16, N=K=256.
// LDS-pipe-bound fix: 4 waves (each owns 64 cols) halves total A-frag LDS
// reads vs 8 waves. Lane owns 4 CONSECUTIVE cols (n0..n0+3) -> float4 x
// prefetch, b64 LDS write, and direct-from-register global h store
// (no LDS round-trip copy).
// ---------------------------------------------------------------------------
__global__ __launch_bounds__(256, 1) void rnn_kernel(
    const float* __restrict__ xp,          // [T][B][H] fp32 (biases folded)
    const float* __restrict__ Whh,
    __hip_bfloat16* __restrict__ hs)       // swizzled A for fc
{
    __shared__ __align__(16) short hbuf[2][16][264];   // +8 pad
    const int tid = threadIdx.x;
    const int l = tid & 63, w = tid >> 6;
    const int lr = l & 15, lh = l >> 4;
    const int n0 = w * 64 + lr * 4;        // 4 consecutive cols n0..n0+3
    // swizzled global base for this lane's column quad (row term added later)
    short* hsg = (short*)hs + ((n0 >> 5) * 512) + (((n0 >> 3) & 3) * 128) + (n0 & 7);

    // B fragments: tile c covers logical col n = n0+c
    bf16x8_t bfrag[4][8];
#pragma unroll
    for (int c = 0; c < 4; c++)
#pragma unroll
        for (int ki = 0; ki < 8; ki++) {
            const float4* p = (const float4*)(Whh + (size_t)(n0 + c) * HID + ki * 32 + lh * 8);
            bfrag[c][ki] = cvt8(p[0], p[1]);
        }
    for (int i = tid; i < 16 * 264; i += 256) ((short*)hbuf[0])[i] = 0;
    __syncthreads();

    float4 xv[4], xw[4];
#pragma unroll
    for (int r = 0; r < 4; r++)
        xv[r] = *(const float4*)(xp + (lh * 4 + r) * HID + n0);

    auto step = [&](int SRC, int DST, float4* xc, float4* xn, int t) {
        bf16x8_t afr[8];
#pragma unroll
        for (int ki = 0; ki < 8; ki++)
            afr[ki] = *(const bf16x8_t*)(&hbuf[SRC][lr][ki * 32 + lh * 8]);

        // per col c: two 4-deep chains; x folded as C-in of chain A
        f32x4_t A0 = {xc[0].x, xc[1].x, xc[2].x, xc[3].x};
        f32x4_t A1 = {xc[0].y, xc[1].y, xc[2].y, xc[3].y};
        f32x4_t A2 = {xc[0].z, xc[1].z, xc[2].z, xc[3].z};
        f32x4_t A3 = {xc[0].w, xc[1].w, xc[2].w, xc[3].w};
        f32x4_t B0 = {0,0,0,0}, B1 = {0,0,0,0}, B2 = {0,0,0,0}, B3 = {0,0,0,0};
#pragma unroll
        for (int ki = 0; ki < 4; ki++) {
            A0 = __builtin_amdgcn_mfma_f32_16x16x32_bf16(afr[ki],     bfrag[0][ki],     A0, 0, 0, 0);
            B0 = __builtin_amdgcn_mfma_f32_16x16x32_bf16(afr[ki + 4], bfrag[0][ki + 4], B0, 0, 0, 0);
            A1 = __builtin_amdgcn_mfma_f32_16x16x32_bf16(afr[ki],     bfrag[1][ki],     A1, 0, 0, 0);
            B1 = __builtin_amdgcn_mfma_f32_16x16x32_bf16(afr[ki + 4], bfrag[1][ki + 4], B1, 0, 0, 0);
            A2 = __builtin_amdgcn_mfma_f32_16x16x32_bf16(afr[ki],     bfrag[2][ki],     A2, 0, 0, 0);
            B2 = __builtin_amdgcn_mfma_f32_16x16x32_bf16(afr[ki + 4], bfrag[2][ki + 4], B2, 0, 0, 0);
            A3 = __builtin_amdgcn_mfma_f32_16x16x32_bf16(afr[ki],     bfrag[3][ki],     A3, 0, 0, 0);
            B3 = __builtin_amdgcn_mfma_f32_16x16x32_bf16(afr[ki + 4], bfrag[3][ki + 4], B3, 0, 0, 0);
        }

        if (t + 1 < SEQT) {
            const float* xb = xp + (size_t)(t + 1) * (BATCH * HID);
#pragma unroll
            for (int r = 0; r < 4; r++)
                xn[r] = *(const float4*)(xb + (lh * 4 + r) * HID + n0);
        }

#pragma unroll
        for (int r = 0; r < 4; r++) {
            float v0 = A0[r] + B0[r];
            float v1 = A1[r] + B1[r];
            float v2 = A2[r] + B2[r];
            float v3 = A3[r] + B3[r];
            uint2 u;
            u.x = pk_bf16(tanh_exp(v0), tanh_exp(v1));
            u.y = pk_bf16(tanh_exp(v2), tanh_exp(v3));
            *(uint2*)(&hbuf[DST][lh * 4 + r][n0]) = u;
            *(uint2*)(hsg + (size_t)t * 4096 + (lh * 4 + r) * 8) = u;  // direct h store
        }
        barrier_lds();
    };

    for (int t = 0; t < SEQT; t += 2) {
        step(0, 1, xv, xw, t);
        step(1, 0, xw, xv, t + 1);
    }
}

// ---------------------------------------------------------------------------
// K3: fused FC GEMM + exp-rowsum + target-logit extraction.
// Stationary-A (64KB LDS, staged once, fragment-swizzled -> linear copy) +
// streamed-B (global->VGPR, double-buffered over flattened 64-step (t,ki)
// sequence; steps independent -> pipeline fills). ONE barrier per block.
// Grid 1024 = 32 m x 32 n-groups; group g pinned to XCD g&7 so its ~512KB
// B panel stays L2-resident while all 32 m-blocks stream it.
// ---------------------------------------------------------------------------
template <bool BF16B>
__global__ __launch_bounds__(256, 2) void fc_kernel(
    const __hip_bfloat16* __restrict__ hsz,   // A swizzled
    const void* __restrict__ WfcP,            // BF16B: swizzled bf16; else raw fp32
    const float* __restrict__ bfc,
    const int* __restrict__ targets,
    float* __restrict__ S,
    float* __restrict__ TL)
{
    __shared__ __align__(16) short As[8 * 4096];   // 64 KB, 8 m-tiles x 8 ki x 1KB
    __shared__ int tgt[128];

    const int bid = blockIdx.x;
    const int x = bid & 7;            // XCD
    const int k = bid >> 3;           // 0..127
    const int g = x + 8 * (k >> 5);   // n-group 0..31 (XCD-bijective)
    const int m_id = k & 31;
    const int m0 = m_id * 128;

    const int tid = threadIdx.x;
    const int l = tid & 63, w = tid >> 6;
    const int lr = l & 15, lh = l >> 4;
    const int wm = (w >> 1) * 64, wn = (w & 1) * 64;

    // stage A panel: 64KB linear copy (already fragment-swizzled in global)
    {
        const short* src = (const short*)hsz + (size_t)m_id * 32768 + tid * 8;
#pragma unroll
        for (int i = 0; i < 16; i++) {
            bf16x8_t v = *(const bf16x8_t*)(src + i * 2048);
            *(bf16x8_t*)(As + i * 2048 + tid * 8) = v;
        }
    }
    if (tid < 128) {
        int r = m0 + tid;                        // r = t*16+b
        tgt[tid] = targets[((r & 15) << 8) | (r >> 4)];
    }
    __syncthreads();   // the only barrier

    int tg[16];
#pragma unroll
    for (int i = 0; i < 16; i++)
        tg[i] = tgt[wm + (i >> 2) * 16 + lh * 4 + (i & 3)];

    const short* Asl = As + (wm >> 4) * 4096 + l * 8;
    const short* Bsw = (const short*)WfcP + (size_t)(wn >> 4) * 4096 + l * 8;
    const float* Bf  = (const float*)WfcP;

    bf16x8_t aa[2][4], bb[2][4];

#define LOADA(buf_, kk_) {                                                   \
    _Pragma("unroll")                                                        \
    for (int mt = 0; mt < 4; mt++)                                           \
        aa[buf_][mt] = *(const bf16x8_t*)(Asl + mt * 4096 + (kk_) * 512); }

#define LOADB(buf_, s_) {                                                    \
    int tt_ = (s_) >> 3, kk_ = (s_) & 7;                                     \
    int nid_ = g * 8 + tt_; if (nid_ >= VOCAB / 128) nid_ = 0;               \
    if (BF16B) {                                                             \
        const short* bp_ = Bsw + (size_t)nid_ * 32768 + kk_ * 512;           \
        _Pragma("unroll")                                                    \
        for (int nt = 0; nt < 4; nt++)                                       \
            bb[buf_][nt] = *(const bf16x8_t*)(bp_ + nt * 4096);              \
    } else {                                                                 \
        _Pragma("unroll")                                                    \
        for (int nt = 0; nt < 4; nt++) {                                     \
            int n_ = nid_ * 128 + wn + nt * 16 + lr;                         \
            const float4* p_ = (const float4*)(Bf + (size_t)n_ * HID         \
                                               + kk_ * 32 + lh * 8);         \
            bb[buf_][nt] = cvt8(p_[0], p_[1]);                               \
        }                                                                    \
    } }

    LOADB(0, 0);
    LOADB(1, 1);
    LOADA(0, 0);

    float rsum[16];
#pragma unroll
    for (int i = 0; i < 16; i++) rsum[i] = 0.f;

    for (int t = 0; t < 8; t++) {
        f32x4_t acc[4][4];
        const f32x4_t z = {0.f, 0.f, 0.f, 0.f};
#pragma unroll
        for (int i = 0; i < 4; i++)
#pragma unroll
            for (int jj = 0; jj < 4; jj++) acc[i][jj] = z;

#pragma unroll
        for (int ki = 0; ki < 8; ki++) {
            LOADA((ki + 1) & 1, (ki + 1) & 7);      // A frags repeat every t
#pragma unroll
            for (int mt = 0; mt < 4; mt++)
#pragma unroll
                for (int nt = 0; nt < 4; nt++)
                    acc[mt][nt] = __builtin_amdgcn_mfma_f32_16x16x32_bf16(
                        aa[ki & 1][mt], bb[ki & 1][nt], acc[mt][nt], 0, 0, 0);
            if (t * 8 + ki + 2 < 64) LOADB(ki & 1, t * 8 + ki + 2);
        }

        int nid = g * 8 + t;
        if (nid < VOCAB / 128) {
#pragma unroll
            for (int nt = 0; nt < 4; nt++) {
                int n = nid * 128 + wn + nt * 16 + lr;
                float bias = bfc[n];
#pragma unroll
                for (int mt = 0; mt < 4; mt++)
#pragma unroll
                    for (int r = 0; r < 4; r++) {
                        float v = acc[mt][nt][r] + bias;
                        rsum[mt * 4 + r] += __expf(v);
                        if (tg[mt * 4 + r] == n)
                            TL[m0 + wm + mt * 16 + lh * 4 + r] = v;
                    }
            }
        }
    }
#undef LOADA
#undef LOADB

#pragma unroll
    for (int m = 1; m < 16; m <<= 1)
#pragma unroll
        for (int i = 0; i < 16; i++) rsum[i] += __shfl_xor(rsum[i], m, 64);
    if (lr == 0) {
#pragma unroll
        for (int i = 0; i < 16; i++) {
            int r = m0 + wm + (i >> 2) * 16 + lh * 4 + (i & 3);
            atomicAdd(&S[r], rsum[i]);
        }
    }
}

// ---------------------------------------------------------------------------
// K4: loss = mean_r( log(S[r]) - TL[r] )
// ---------------------------------------------------------------------------
__global__ __launch_bounds__(256) void loss_kernel(
    const float* __restrict__ S,
    const float* __restrict__ TL,
    float* __restrict__ out)
{
    int tid = threadIdx.x;
    float p = 0.f;
    for (int i = tid; i < ROWS; i += 256) p += __logf(S[i]) - TL[i];
#pragma unroll
    for (int m = 1; m < 64; m <<= 1) p += __shfl_xor(p, m, 64);
    __shared__ float red[4];
    if ((tid & 63) == 0) red[tid >> 6] = p;
    __syncthreads();
    if (tid == 0)
        out[0] = (red[0] + red[1] + red[2] + red[3]) / (float)ROWS;
}

extern "C" void kernel_launch(void* const* d_in, const int* in_sizes, int n_in,
                              void* d_out, int out_size, void* d_ws, size_t ws_size,
                              hipStream_t stream)
{
    (void)in_sizes; (void)n_in; (void)out_size;
    const int*   inputs  = (const int*)d_in[0];
    const int*   targets = (const int*)d_in[1];
    const float* Wih = (const float*)d_in[2];
    const float* bih = (const float*)d_in[3];
    const float* Whh = (const float*)d_in[4];
    const float* bhh = (const float*)d_in[5];
    const float* Wfc = (const float*)d_in[6];
    const float* bfc = (const float*)d_in[7];

    float* S  = (float*)d_ws;                           // 4096 f32
    float* TL = S + ROWS;                               // 4096 f32
    float* xp = TL + ROWS;                              // [T][B][H] fp32, 4 MB
    __hip_bfloat16* hs = (__hip_bfloat16*)(xp + (size_t)SEQT * BATCH * HID); // 2 MB (swizzled)
    __hip_bfloat16* Wfcb = hs + (size_t)ROWS * HID;     // 32000x256 bf16 swizzled, 16 MB

    const size_t need = (size_t)(2 * ROWS) * 4 + (size_t)ROWS * HID * 4
                      + (size_t)ROWS * HID * 2 + (size_t)VOCAB * HID * 2;
    const int use_bf16b = (ws_size >= need) ? 1 : 0;

    xproj_kernel<<<(SEQT * BATCH * HID) / 256, 256, 0, stream>>>(
        inputs, Wih, bih, bhh, Wfc, xp, S, Wfcb, use_bf16b);
    rnn_kernel<<<1, 256, 0, stream>>>(xp, Whh, hs);
    if (use_bf16b)
        fc_kernel<true><<<1024, 256, 0, stream>>>(hs, (const void*)Wfcb, bfc, targets, S, TL);
    else
        fc_kernel<false><<<1024, 256, 0, stream>>>(hs, (const void*)Wfc, bfc, targets, S, TL);
    loss_kernel<<<1, 256, 0, stream>>>(S, TL, (float*)d_out);
}

// Round 4
// 470.746 us; speedup vs baseline: 1.9123x; 1.9123x over previous
//
#include <hip/hip_runtime.h>
#include <hip/hip_bf16.h>
#include <stdint.h>

#define VOCAB 32000
#define HID   256
#define BATCH 16
#define SEQT  256
#define ROWS  (BATCH*SEQT)   // 4096

typedef __attribute__((ext_vector_type(8))) short bf16x8_t;
typedef __attribute__((ext_vector_type(4))) float f32x4_t;

__device__ __forceinline__ short f2bs(float x) {
    __hip_bfloat16 h = __float2bfloat16(x);
    return *reinterpret_cast<short*>(&h);
}
__device__ __forceinline__ bf16x8_t cvt8(float4 a, float4 b) {
    union { short s[8]; bf16x8_t v; } u;
    u.s[0] = f2bs(a.x); u.s[1] = f2bs(a.y); u.s[2] = f2bs(a.z); u.s[3] = f2bs(a.w);
    u.s[4] = f2bs(b.x); u.s[5] = f2bs(b.y); u.s[6] = f2bs(b.z); u.s[7] = f2bs(b.w);
    return u.v;
}
// workgroup barrier draining ONLY lgkmcnt; vmem stays in flight
__device__ __forceinline__ void barrier_lds() {
    asm volatile("s_waitcnt lgkmcnt(0)\n\ts_barrier" ::: "memory");
}
// tanh via exp2: tanh(x) = 1 - 2/(2^(2*log2(e)*x)+1); saturates naturally.
__device__ __forceinline__ float tanh_exp(float x) {
    float e = __builtin_amdgcn_exp2f(x * 2.885390081777927f);
    return fmaf(-2.f, __builtin_amdgcn_rcpf(e + 1.f), 1.f);
}
// pack two f32 -> one dword of 2 bf16 (RNE), lo = first operand
__device__ __forceinline__ uint32_t pk_bf16(float lo, float hi) {
    uint32_t r;
    asm("v_cvt_pk_bf16_f32 %0, %1, %2" : "=v"(r) : "v"(lo), "v"(hi));
    return r;
}
// async global->LDS, 16B per lane: LDS dest = wave-uniform base + lane*16,
// global src = per-lane pointer. Counts against vmcnt.
__device__ __forceinline__ void gload_lds16(const short* g, short* lds_base) {
    __builtin_amdgcn_global_load_lds(
        (const __attribute__((address_space(1))) void*)g,
        (__attribute__((address_space(3))) void*)lds_base, 16, 0, 0);
}

// ===========================================================================
// Swizzled fragment layout (shared by A=hs and B=Wfcb):
//   element (row, k) -> swz[ (row>>4)*4096 + (k>>5)*512 + ((k>>3)&3)*128
//                            + (row&15)*8 + (k&7) ]
// Within a fragment (one 16-row tile, one ki) the data is LANE-LINEAR:
// lane l's 8 elements live at offset l*8 -> a fragment is 1 KB contiguous,
// stageable by ONE global_load_lds wave-instruction (linear LDS dest).
// ===========================================================================

// ---------------------------------------------------------------------------
// K1: xp[t][b][h] = Wih[inputs[b][t]][h]+bih[h]+bhh[h]; zeroes S; converts
// Wfc fp32 -> bf16 into SWIZZLED Wfcb (coalesced-write direction).
// ---------------------------------------------------------------------------
__global__ __launch_bounds__(256) void xproj_kernel(
    const int* __restrict__ inputs,
    const float* __restrict__ Wih,
    const float* __restrict__ bih,
    const float* __restrict__ bhh,
    const float* __restrict__ Wfc,
    float* __restrict__ xp,
    float* __restrict__ S,
    __hip_bfloat16* __restrict__ Wfcb,
    int do_cvt)
{
    int idx = blockIdx.x * 256 + threadIdx.x;  // (t*16+b)*256 + h
    int h  = idx & 255;
    int tb = idx >> 8;
    int b  = tb & 15;
    int t  = tb >> 4;
    int id = inputs[b * SEQT + t];
    xp[idx] = Wih[(size_t)id * HID + h] + bih[h] + bhh[h];
    if (idx < ROWS) S[idx] = 0.0f;
    if (do_cvt && idx < (VOCAB * HID / 8)) {
        // dst-linear: e = idx*8 shorts in swizzled Wfcb; decode -> (row,k)
        int e   = idx * 8;
        int m   = (e >> 3) & 15;
        int lhh = (e >> 7) & 3;
        int ki  = (e >> 9) & 7;
        int tile = e >> 12;
        const float4* p = (const float4*)(Wfc + (size_t)(tile * 16 + m) * HID
                                          + ki * 32 + lhh * 8);
        *(bf16x8_t*)((short*)Wfcb + (size_t)e) = cvt8(p[0], p[1]);
    }
}

// ---------------------------------------------------------------------------
// K2: RNN recurrence. One block, 256 threads (4 waves), M=16, N=K=256.
// Each wave owns 64 cols; lane owns 4 consecutive cols -> float4 x prefetch,
// b64 LDS write, direct-from-register swizzled global h store.
// ---------------------------------------------------------------------------
__global__ __launch_bounds__(256, 1) void rnn_kernel(
    const float* __restrict__ xp,          // [T][B][H] fp32 (biases folded)
    const float* __restrict__ Whh,
    __hip_bfloat16* __restrict__ hs)       // swizzled A for fc
{
    __shared__ __align__(16) short hbuf[2][16][264];   // +8 pad
    const int tid = threadIdx.x;
    const int l = tid & 63, w = tid >> 6;
    const int lr = l & 15, lh = l >> 4;
    const int n0 = w * 64 + lr * 4;        // 4 consecutive cols n0..n0+3
    // swizzled global base for this lane's column quad (row term added later)
    short* hsg = (short*)hs + ((n0 >> 5) * 512) + (((n0 >> 3) & 3) * 128) + (n0 & 7);

    // B fragments: tile c covers logical col n = n0+c
    bf16x8_t bfrag[4][8];
#pragma unroll
    for (int c = 0; c < 4; c++)
#pragma unroll
        for (int ki = 0; ki < 8; ki++) {
            const float4* p = (const float4*)(Whh + (size_t)(n0 + c) * HID + ki * 32 + lh * 8);
            bfrag[c][ki] = cvt8(p[0], p[1]);
        }
    for (int i = tid; i < 16 * 264; i += 256) ((short*)hbuf[0])[i] = 0;
    __syncthreads();

    float4 xv[4], xw[4];
#pragma unroll
    for (int r = 0; r < 4; r++)
        xv[r] = *(const float4*)(xp + (lh * 4 + r) * HID + n0);

    auto step = [&](int SRC, int DST, float4* xc, float4* xn, int t) {
        bf16x8_t afr[8];
#pragma unroll
        for (int ki = 0; ki < 8; ki++)
            afr[ki] = *(const bf16x8_t*)(&hbuf[SRC][lr][ki * 32 + lh * 8]);

        // per col c: two 4-deep chains; x folded as C-in of chain A
        f32x4_t A0 = {xc[0].x, xc[1].x, xc[2].x, xc[3].x};
        f32x4_t A1 = {xc[0].y, xc[1].y, xc[2].y, xc[3].y};
        f32x4_t A2 = {xc[0].z, xc[1].z, xc[2].z, xc[3].z};
        f32x4_t A3 = {xc[0].w, xc[1].w, xc[2].w, xc[3].w};
        f32x4_t B0 = {0,0,0,0}, B1 = {0,0,0,0}, B2 = {0,0,0,0}, B3 = {0,0,0,0};
#pragma unroll
        for (int ki = 0; ki < 4; ki++) {
            A0 = __builtin_amdgcn_mfma_f32_16x16x32_bf16(afr[ki],     bfrag[0][ki],     A0, 0, 0, 0);
            B0 = __builtin_amdgcn_mfma_f32_16x16x32_bf16(afr[ki + 4], bfrag[0][ki + 4], B0, 0, 0, 0);
            A1 = __builtin_amdgcn_mfma_f32_16x16x32_bf16(afr[ki],     bfrag[1][ki],     A1, 0, 0, 0);
            B1 = __builtin_amdgcn_mfma_f32_16x16x32_bf16(afr[ki + 4], bfrag[1][ki + 4], B1, 0, 0, 0);
            A2 = __builtin_amdgcn_mfma_f32_16x16x32_bf16(afr[ki],     bfrag[2][ki],     A2, 0, 0, 0);
            B2 = __builtin_amdgcn_mfma_f32_16x16x32_bf16(afr[ki + 4], bfrag[2][ki + 4], B2, 0, 0, 0);
            A3 = __builtin_amdgcn_mfma_f32_16x16x32_bf16(afr[ki],     bfrag[3][ki],     A3, 0, 0, 0);
            B3 = __builtin_amdgcn_mfma_f32_16x16x32_bf16(afr[ki + 4], bfrag[3][ki + 4], B3, 0, 0, 0);
        }

        if (t + 1 < SEQT) {
            const float* xb = xp + (size_t)(t + 1) * (BATCH * HID);
#pragma unroll
            for (int r = 0; r < 4; r++)
                xn[r] = *(const float4*)(xb + (lh * 4 + r) * HID + n0);
        }

#pragma unroll
        for (int r = 0; r < 4; r++) {
            float v0 = A0[r] + B0[r];
            float v1 = A1[r] + B1[r];
            float v2 = A2[r] + B2[r];
            float v3 = A3[r] + B3[r];
            uint2 u;
            u.x = pk_bf16(tanh_exp(v0), tanh_exp(v1));
            u.y = pk_bf16(tanh_exp(v2), tanh_exp(v3));
            *(uint2*)(&hbuf[DST][lh * 4 + r][n0]) = u;
            *(uint2*)(hsg + (size_t)t * 4096 + (lh * 4 + r) * 8) = u;  // direct h store
        }
        barrier_lds();
    };

    for (int t = 0; t < SEQT; t += 2) {
        step(0, 1, xv, xw, t);
        step(1, 0, xw, xv, t + 1);
    }
}

// ---------------------------------------------------------------------------
// K3: fused FC GEMM + exp-rowsum + target-logit extraction.
// R1 skeleton (8192 blocks, 128x128 tile, XCD swizzle -> FETCH 16MB) with
// global_load_lds staging (zero VALU, zero staging VGPRs) and counted-vmcnt
// 2-phase pipeline: stage slab s+2 while computing s; vmcnt(4) steady state
// (2 slabs in flight, never drained); lgkm-only barriers.
// NO occupancy bound -> no spill (R3 lesson).
// ---------------------------------------------------------------------------
template <bool BF16B>
__global__ __launch_bounds__(256) void fc_kernel(
    const __hip_bfloat16* __restrict__ hsz,   // A swizzled
    const void* __restrict__ WfcP,            // BF16B: swizzled bf16; else raw fp32
    const float* __restrict__ bfc,
    const int* __restrict__ targets,
    float* __restrict__ S,
    float* __restrict__ TL)
{
    __shared__ __align__(16) short As[2][8 * 512];   // [buf][tile 0..7][lane*8]
    __shared__ __align__(16) short Bs[2][8 * 512];
    __shared__ int tgt[128];

    const int bid = blockIdx.x;
    const int xcd = bid & 7;
    const int j   = bid >> 3;
    const int m_id = j & 31;
    const int n_id = (j >> 5) * 8 + xcd;
    if (n_id >= VOCAB / 128) return;
    const int m0 = m_id * 128, n0 = n_id * 128;

    const int tid = threadIdx.x;
    const int l = tid & 63, w = tid >> 6;
    const int lr = l & 15, lh = l >> 4;
    const int wm = (w >> 1) * 64, wn = (w & 1) * 64;

    // tgt staging first; the dependent ds_write forces a vmcnt drain, so the
    // counted-vmcnt math below starts from 0 on every wave.
    if (tid < 128) {
        int r = m0 + tid;                        // r = t*16+b
        tgt[tid] = targets[((r & 15) << 8) | (r >> 4)];
    }
    __builtin_amdgcn_sched_barrier(0);

    // per-wave staging: wave w stages A tiles {2w,2w+1} and B tiles {2w,2w+1}
    const short* Ag = (const short*)hsz + (size_t)m_id * 32768 + (size_t)(w * 2) * 4096 + l * 8;
    const short* Bg = (const short*)WfcP + (size_t)n_id * 32768 + (size_t)(w * 2) * 4096 + l * 8;
    const float* Bf = (const float*)WfcP;

    f32x4_t acc[4][4];
    const f32x4_t z = {0.f, 0.f, 0.f, 0.f};
#pragma unroll
    for (int i = 0; i < 4; i++)
#pragma unroll
        for (int jj = 0; jj < 4; jj++) acc[i][jj] = z;

    if (BF16B) {
        // stage = 4 wave-instructions: A tiles 2w,2w+1 + B tiles 2w,2w+1, slab s
        auto stage = [&](int buf, int s) {
            gload_lds16(Ag + s * 512,        &As[buf][(w * 2) * 512]);
            gload_lds16(Ag + 4096 + s * 512, &As[buf][(w * 2 + 1) * 512]);
            gload_lds16(Bg + s * 512,        &Bs[buf][(w * 2) * 512]);
            gload_lds16(Bg + 4096 + s * 512, &Bs[buf][(w * 2 + 1) * 512]);
        };
        stage(0, 0);
        stage(1, 1);
        __builtin_amdgcn_sched_barrier(0);

#pragma unroll
        for (int s = 0; s < 8; s++) {
            const int buf = s & 1;
            // wait own stage(s) landed (FIFO: 4 newer ops may remain), then
            // barrier -> everyone's stage(s) is in LDS
            if (s < 7) asm volatile("s_waitcnt vmcnt(4)\n\ts_barrier" ::: "memory");
            else       asm volatile("s_waitcnt vmcnt(0)\n\ts_barrier" ::: "memory");

            bf16x8_t a[4], b[4];
#pragma unroll
            for (int mt = 0; mt < 4; mt++)
                a[mt] = *(const bf16x8_t*)&As[buf][(((w >> 1) * 4 + mt) * 512) + l * 8];
#pragma unroll
            for (int nt = 0; nt < 4; nt++)
                b[nt] = *(const bf16x8_t*)&Bs[buf][(((w & 1) * 4 + nt) * 512) + l * 8];

            if (s < 6) {
                barrier_lds();            // all waves done reading buf
                stage(buf, s + 2);        // refill buf 2 slabs ahead
                __builtin_amdgcn_sched_barrier(0);
            }
#pragma unroll
            for (int mt = 0; mt < 4; mt++)
#pragma unroll
                for (int nt = 0; nt < 4; nt++)
                    acc[mt][nt] = __builtin_amdgcn_mfma_f32_16x16x32_bf16(
                        a[mt], b[nt], acc[mt][nt], 0, 0, 0);
        }
    } else {
        // fallback (tiny workspace): register staging, single buffer, simple barriers
        for (int s = 0; s < 8; s++) {
            __syncthreads();
#pragma unroll
            for (int i = 0; i < 2; i++) {
                int tt = w * 2 + i;
                bf16x8_t va = *(const bf16x8_t*)(Ag + i * 4096 + s * 512);
                *(bf16x8_t*)&As[0][tt * 512 + l * 8] = va;
                int n = n0 + tt * 16 + lr;
                const float4* p = (const float4*)(Bf + (size_t)n * HID + s * 32 + lh * 8);
                *(bf16x8_t*)&Bs[0][tt * 512 + l * 8] = cvt8(p[0], p[1]);
            }
            __syncthreads();
            bf16x8_t a[4], b[4];
#pragma unroll
            for (int mt = 0; mt < 4; mt++)
                a[mt] = *(const bf16x8_t*)&As[0][(((w >> 1) * 4 + mt) * 512) + l * 8];
#pragma unroll
            for (int nt = 0; nt < 4; nt++)
                b[nt] = *(const bf16x8_t*)&Bs[0][(((w & 1) * 4 + nt) * 512) + l * 8];
#pragma unroll
            for (int mt = 0; mt < 4; mt++)
#pragma unroll
                for (int nt = 0; nt < 4; nt++)
                    acc[mt][nt] = __builtin_amdgcn_mfma_f32_16x16x32_bf16(
                        a[mt], b[nt], acc[mt][nt], 0, 0, 0);
        }
    }

    // epilogue: bias + exp + rowsum; extract target logits inline
    int tg[16];
#pragma unroll
    for (int i = 0; i < 16; i++)
        tg[i] = tgt[wm + (i >> 2) * 16 + lh * 4 + (i & 3)];

    float rsum[16];
#pragma unroll
    for (int i = 0; i < 16; i++) rsum[i] = 0.f;
#pragma unroll
    for (int nt = 0; nt < 4; nt++) {
        int n = n0 + wn + nt * 16 + lr;
        float bias = bfc[n];
#pragma unroll
        for (int mt = 0; mt < 4; mt++)
#pragma unroll
            for (int r = 0; r < 4; r++) {
                float v = acc[mt][nt][r] + bias;
                rsum[mt * 4 + r] += __expf(v);
                if (tg[mt * 4 + r] == n)
                    TL[m0 + wm + mt * 16 + lh * 4 + r] = v;
            }
    }
#pragma unroll
    for (int m = 1; m < 16; m <<= 1)
#pragma unroll
        for (int i = 0; i < 16; i++) rsum[i] += __shfl_xor(rsum[i], m, 64);
    if (lr == 0) {
#pragma unroll
        for (int i = 0; i < 16; i++) {
            int r = m0 + wm + (i >> 2) * 16 + lh * 4 + (i & 3);
            atomicAdd(&S[r], rsum[i]);
        }
    }
}

// ---------------------------------------------------------------------------
// K4: loss = mean_r( log(S[r]) - TL[r] )
// ---------------------------------------------------------------------------
__global__ __launch_bounds__(256) void loss_kernel(
    const float* __restrict__ S,
    const float* __restrict__ TL,
    float* __restrict__ out)
{
    int tid = threadIdx.x;
    float p = 0.f;
    for (int i = tid; i < ROWS; i += 256) p += __logf(S[i]) - TL[i];
#pragma unroll
    for (int m = 1; m < 64; m <<= 1) p += __shfl_xor(p, m, 64);
    __shared__ float red[4];
    if ((tid & 63) == 0) red[tid >> 6] = p;
    __syncthreads();
    if (tid == 0)
        out[0] = (red[0] + red[1] + red[2] + red[3]) / (float)ROWS;
}

extern "C" void kernel_launch(void* const* d_in, const int* in_sizes, int n_in,
                              void* d_out, int out_size, void* d_ws, size_t ws_size,
                              hipStream_t stream)
{
    (void)in_sizes; (void)n_in; (void)out_size;
    const int*   inputs  = (const int*)d_in[0];
    const int*   targets = (const int*)d_in[1];
    const float* Wih = (const float*)d_in[2];
    const float* bih = (const float*)d_in[3];
    const float* Whh = (const float*)d_in[4];
    const float* bhh = (const float*)d_in[5];
    const float* Wfc = (const float*)d_in[6];
    const float* bfc = (const float*)d_in[7];

    float* S  = (float*)d_ws;                           // 4096 f32
    float* TL = S + ROWS;                               // 4096 f32
    float* xp = TL + ROWS;                              // [T][B][H] fp32, 4 MB
    __hip_bfloat16* hs = (__hip_bfloat16*)(xp + (size_t)SEQT * BATCH * HID); // 2 MB (swizzled)
    __hip_bfloat16* Wfcb = hs + (size_t)ROWS * HID;     // 32000x256 bf16 swizzled, 16 MB

    const size_t need = (size_t)(2 * ROWS) * 4 + (size_t)ROWS * HID * 4
                      + (size_t)ROWS * HID * 2 + (size_t)VOCAB * HID * 2;
    const int use_bf16b = (ws_size >= need) ? 1 : 0;

    xproj_kernel<<<(SEQT * BATCH * HID) / 256, 256, 0, stream>>>(
        inputs, Wih, bih, bhh, Wfc, xp, S, Wfcb, use_bf16b);
    rnn_kernel<<<1, 256, 0, stream>>>(xp, Whh, hs);
    if (use_bf16b)
        fc_kernel<true><<<8192, 256, 0, stream>>>(hs, (const void*)Wfcb, bfc, targets, S, TL);
    else
        fc_kernel<false><<<8192, 256, 0, stream>>>(hs, (const void*)Wfc, bfc, targets, S, TL);
    loss_kernel<<<1, 256, 0, stream>>>(S, TL, (float*)d_out);
}